// Round 12
// baseline (34.908 us; speedup 1.0000x reference)
//
#include <hip/hip_runtime.h>

#define NWIN 121
#define NQ 10
#define NGATES 23

typedef float v2f __attribute__((ext_vector_type(2)));

// type 0 = fused conv block (u3⊗u3 · XX·YY·ZZ · u3⊗u3), type 1 = CRot.
__device__ static const int dGT[NGATES] = {0,0,0,0,0,0,0,0,0, 1,1,1,1,1, 0,0,0,0, 1,1, 0,0, 1};
__device__ static const int dGL[NGATES] = {0,0,0,0,0,0,0,0,0, 0,0,0,0,0, 1,1,1,1, 1,1, 2,2, 2};
__device__ static const int dGP[NGATES] = {0,2,4,6,8,1,3,5,7, 0,1,2,3,4, 0,2,1,3, 0,1, 0,1, 0};

struct cpx { float x, y; };
__device__ __forceinline__ cpx cmul(cpx a, cpx b){ return {a.x*b.x - a.y*b.y, a.x*b.y + a.y*b.x}; }
__device__ __forceinline__ cpx cadd(cpx a, cpx b){ return {a.x+b.x, a.y+b.y}; }
__device__ __forceinline__ cpx cscale(float s, cpx a){ return {s*a.x, s*a.y}; }
__device__ __forceinline__ cpx cexp_i(float t){ return {cosf(t), sinf(t)}; }
__device__ __forceinline__ cpx mulnegi(cpx z){ return {z.y, -z.x}; }   // -i*z
__device__ __forceinline__ cpx csel(int c, cpx a, cpx b){ return {c ? a.x : b.x, c ? a.y : b.y}; }

__device__ __forceinline__ void u3m(cpx A[2][2], float th, float ph, float de){
    float ct = cosf(0.5f*th), st = sinf(0.5f*th);
    cpx ed  = cexp_i(de);
    cpx ep  = cexp_i(ph);
    cpx epd = cexp_i(ph + de);
    A[0][0] = {ct, 0.f};
    A[0][1] = {-ed.x*st, -ed.y*st};
    A[1][0] = { ep.x*st,  ep.y*st};
    A[1][1] = { epd.x*ct, epd.y*ct};
}

// Build COLUMN c of fused gate g's 4x4 matrix. ALL array indices static
// (rule-#20 safe; runtime column choice via csel/cndmask — the r9 fix).
__device__ __forceinline__ void build_gate_col(int g, int c,
                                               const float* __restrict__ conv,
                                               const float* __restrict__ pool,
                                               cpx (&Mc)[4])
{
    int l = dGL[g], pi = dGP[g];
    if (dGT[g] == 0) {
        const float* W1 = conv + l*150 + pi*15;
        const float* W2 = conv + l*150 + (pi+1)*15;
        cpx A1[2][2], B1[2][2], A2[2][2], B2[2][2];
        u3m(A1, W1[0],  W1[1],  W1[2]);
        u3m(B1, W2[3],  W2[4],  W2[5]);
        u3m(A2, W1[9],  W1[10], W1[11]);
        u3m(B2, W2[12], W2[13], W2[14]);
        const int c1 = c >> 1, c2 = c & 1;
        cpx a1r0 = csel(c1, A1[0][1], A1[0][0]);
        cpx a1r1 = csel(c1, A1[1][1], A1[1][0]);
        cpx b1r0 = csel(c2, B1[0][1], B1[0][0]);
        cpx b1r1 = csel(c2, B1[1][1], B1[1][0]);
        cpx T[4];
        T[0] = cmul(a1r0, b1r0);
        T[1] = cmul(a1r0, b1r1);
        T[2] = cmul(a1r1, b1r0);
        T[3] = cmul(a1r1, b1r1);
        float tz = W1[6];
        cpx em = cexp_i(-0.5f*tz), ep = cexp_i(0.5f*tz);
        T[0] = cmul(em, T[0]); T[1] = cmul(ep, T[1]);
        T[2] = cmul(ep, T[2]); T[3] = cmul(em, T[3]);
        float ty = W1[7]; float cy = cosf(0.5f*ty), sy = sinf(0.5f*ty);
        cpx T2_[4];
        T2_[0] = cadd(cscale(cy,T[0]), mulnegi(cscale(-sy, T[3])));
        T2_[1] = cadd(cscale(cy,T[1]), mulnegi(cscale( sy, T[2])));
        T2_[2] = cadd(cscale(cy,T[2]), mulnegi(cscale( sy, T[1])));
        T2_[3] = cadd(cscale(cy,T[3]), mulnegi(cscale(-sy, T[0])));
        float tx = W1[8]; float cx = cosf(0.5f*tx), sx = sinf(0.5f*tx);
        cpx T3_[4];
        T3_[0] = cadd(cscale(cx,T2_[0]), mulnegi(cscale(sx, T2_[3])));
        T3_[1] = cadd(cscale(cx,T2_[1]), mulnegi(cscale(sx, T2_[2])));
        T3_[2] = cadd(cscale(cx,T2_[2]), mulnegi(cscale(sx, T2_[1])));
        T3_[3] = cadd(cscale(cx,T2_[3]), mulnegi(cscale(sx, T2_[0])));
        cpx K2[4][4];
        #pragma unroll
        for (int r1=0;r1<2;++r1)
        #pragma unroll
        for (int r2=0;r2<2;++r2)
        #pragma unroll
        for (int d1=0;d1<2;++d1)
        #pragma unroll
        for (int d2=0;d2<2;++d2)
            K2[2*r1+r2][2*d1+d2] = cmul(A2[r1][d1], B2[r2][d2]);
        #pragma unroll
        for (int r=0;r<4;++r) {
            cpx acc = {0.f, 0.f};
            #pragma unroll
            for (int m=0;m<4;++m) acc = cadd(acc, cmul(K2[r][m], T3_[m]));
            Mc[r] = acc;
        }
    } else {
        const float* Pp = pool + l*15 + pi*3;
        float phi = Pp[0], th = Pp[1], om = Pp[2];
        float ct = cosf(0.5f*th), st = sinf(0.5f*th);
        cpx z = {0.f, 0.f}, one = {1.f, 0.f};
        cpx m22 = cscale( ct, cexp_i(-0.5f*(phi+om)));
        cpx m32 = cscale( st, cexp_i(-0.5f*(phi-om)));
        cpx m23 = cscale(-st, cexp_i( 0.5f*(phi-om)));
        cpx m33 = cscale( ct, cexp_i( 0.5f*(phi+om)));
        Mc[0] = csel(c == 0, one, z);
        Mc[1] = csel(c == 1, one, z);
        Mc[2] = csel(c == 2, m22, csel(c == 3, m23, z));
        Mc[3] = csel(c == 2, m32, csel(c == 3, m33, z));
    }
}

// ---- sim helpers -----------------------------------------------------------

__device__ __forceinline__ v2f cfma(v2f m, v2f v, v2f acc) {
    v2f sw = {v.y, v.x};
    v2f my = {-m.y, m.y};
    v2f t = __builtin_elementwise_fma(my, sw, acc);
    v2f mx = {m.x, m.x};
    return __builtin_elementwise_fma(mx, v, t);
}
__device__ __forceinline__ v2f cmulv(v2f a, v2f b) { return cfma(a, b, (v2f){0.f,0.f}); }
__device__ __forceinline__ v2f vsel(int c, v2f a, v2f b) {
    return (v2f){ c ? a.x : b.x, c ? a.y : b.y };
}
__device__ __forceinline__ v2f vshfl(v2f v, int m) {
    return (v2f){ __shfl_xor(v.x, m), __shfl_xor(v.y, m) };
}

__device__ __forceinline__ void load16(const float2* __restrict__ g, v2f (&m)[16]) {
    const float4* g4 = reinterpret_cast<const float4*>(g);
    #pragma unroll
    for (int k = 0; k < 8; ++k) {
        float4 t = g4[k];
        m[2*k]   = (v2f){t.x, t.y};
        m[2*k+1] = (v2f){t.z, t.w};
    }
}
__device__ __forceinline__ void load4(const float2* __restrict__ g, v2f (&c4)[4]) {
    const float4* g4 = reinterpret_cast<const float4*>(g);
    float4 a = g4[5], b = g4[7];
    c4[0] = (v2f){a.x,a.y}; c4[1] = (v2f){a.z,a.w};   // m22 m23
    c4[2] = (v2f){b.x,b.y}; c4[3] = (v2f){b.z,b.w};   // m32 m33
}

// dense gate, both bits in reg index: k = 2*bit_P1 + bit_P2. 8-reg state.
template<int P1, int P2>
__device__ __forceinline__ void gateRR(v2f (&st)[8], const float2* __restrict__ g) {
    v2f m[16]; load16(g, m);
    constexpr int M1 = 1 << P1, M2 = 1 << P2;
    #pragma unroll
    for (int b = 0; b < 8; ++b) {
        if (b & (M1 | M2)) continue;
        v2f v0 = st[b], v1 = st[b|M2], v2 = st[b|M1], v3 = st[b|M1|M2];
        #pragma unroll
        for (int row = 0; row < 4; ++row) {
            v2f acc = cfma(m[row*4+0], v0, (v2f){0.f, 0.f});
            acc = cfma(m[row*4+1], v1, acc);
            acc = cfma(m[row*4+2], v2, acc);
            acc = cfma(m[row*4+3], v3, acc);
            st[b | ((row>>1) ? M1 : 0) | ((row&1) ? M2 : 0)] = acc;
        }
    }
}

// dense gate, first bit at reg pos PREG, second at lane mask LM (shfl_xor).
template<int PREG, int LM>
__device__ __forceinline__ void gateRL(v2f (&st)[8], const float2* __restrict__ g, int lane) {
    v2f m[16]; load16(g, m);
    const int beta = (lane & LM) ? 1 : 0;
    v2f A00 = vsel(beta, m[5],  m[0]);
    v2f A01 = vsel(beta, m[4],  m[1]);
    v2f A02 = vsel(beta, m[7],  m[2]);
    v2f A03 = vsel(beta, m[6],  m[3]);
    v2f A10 = vsel(beta, m[13], m[8]);
    v2f A11 = vsel(beta, m[12], m[9]);
    v2f A12 = vsel(beta, m[15], m[10]);
    v2f A13 = vsel(beta, m[14], m[11]);
    constexpr int M1 = 1 << PREG;
    #pragma unroll
    for (int b = 0; b < 8; ++b) {
        if (b & M1) continue;
        v2f u0 = st[b], u1 = st[b|M1];
        v2f p0 = vshfl(u0, LM), p1 = vshfl(u1, LM);
        v2f r0 = cfma(A03, p1, cfma(A02, u1, cfma(A01, p0, cmulv(A00, u0))));
        v2f r1 = cfma(A13, p1, cfma(A12, u1, cfma(A11, p0, cmulv(A10, u0))));
        st[b] = r0; st[b|M1] = r1;
    }
}

// dense gate, both bits in lane space: k = 2*(lane&M1?) + (lane&M2?).
template<int M1L, int M2L>
__device__ __forceinline__ void gateLL(v2f (&st)[8], const float2* __restrict__ g, int lane) {
    v2f m[16]; load16(g, m);
    const int kb1 = (lane & M1L) ? 1 : 0;
    const int kb0 = (lane & M2L) ? 1 : 0;
    v2f C0 = vsel(kb1, vsel(kb0, m[15], m[10]), vsel(kb0, m[5],  m[0]));
    v2f C1 = vsel(kb1, vsel(kb0, m[14], m[11]), vsel(kb0, m[4],  m[1]));
    v2f C2 = vsel(kb1, vsel(kb0, m[13], m[8]),  vsel(kb0, m[7],  m[2]));
    v2f C3 = vsel(kb1, vsel(kb0, m[12], m[9]),  vsel(kb0, m[6],  m[3]));
    #pragma unroll
    for (int r = 0; r < 8; ++r) {
        v2f u  = st[r];
        v2f q1 = vshfl(u, M2L);
        v2f q2 = vshfl(u, M1L);
        v2f q3 = vshfl(u, M1L | M2L);
        st[r] = cfma(C3, q3, cfma(C2, q2, cfma(C1, q1, cmulv(C0, u))));
    }
}

// CRot, ctrl and tgt both reg bits.
template<int CTRL, int TGT>
__device__ __forceinline__ void crotRR(v2f (&st)[8], const float2* __restrict__ g) {
    v2f c4[4]; load4(g, c4);
    constexpr int MC = 1 << CTRL, MT = 1 << TGT;
    #pragma unroll
    for (int b = 0; b < 8; ++b) {
        if (!(b & MC) || (b & MT)) continue;
        v2f v2_ = st[b], v3_ = st[b|MT];
        st[b]    = cfma(c4[1], v3_, cmulv(c4[0], v2_));
        st[b|MT] = cfma(c4[3], v3_, cmulv(c4[2], v2_));
    }
}

// CRot, ctrl at lane mask CM, tgt at reg pos TR (identity-blend, branchless).
template<int CM, int TR>
__device__ __forceinline__ void crotLR(v2f (&st)[8], const float2* __restrict__ g, int lane) {
    v2f c4[4]; load4(g, c4);
    const int beta = (lane & CM) ? 1 : 0;
    const v2f one = {1.f, 0.f}, zero = {0.f, 0.f};
    v2f c00 = vsel(beta, c4[0], one);
    v2f c01 = vsel(beta, c4[1], zero);
    v2f c10 = vsel(beta, c4[2], zero);
    v2f c11 = vsel(beta, c4[3], one);
    constexpr int MT = 1 << TR;
    #pragma unroll
    for (int b = 0; b < 8; ++b) {
        if (b & MT) continue;
        v2f u = st[b], v = st[b|MT];
        st[b]    = cfma(c01, v, cmulv(c00, u));
        st[b|MT] = cfma(c11, v, cmulv(c10, u));
    }
}

// CRot, ctrl at lane mask CM, tgt at lane mask TM.
template<int CM, int TM>
__device__ __forceinline__ void crotLL(v2f (&st)[8], const float2* __restrict__ g, int lane) {
    v2f c4[4]; load4(g, c4);
    const int ctl = (lane & CM) ? 1 : 0;
    const int tgt = (lane & TM) ? 1 : 0;
    const v2f one = {1.f, 0.f}, zero = {0.f, 0.f};
    v2f c0 = vsel(ctl, vsel(tgt, c4[3], c4[0]), one);
    v2f c1 = vsel(ctl, vsel(tgt, c4[2], c4[1]), zero);
    #pragma unroll
    for (int r = 0; r < 8; ++r) {
        v2f p = vshfl(st[r], TM);
        st[r] = cfma(c1, p, cmulv(c0, st[r]));
    }
}

// Two-wave-per-sample fused kernel. Block = 256 threads = 4 waves = 2 samples.
// Per sample: 1024 amps = 2 waves x 64 lanes x 8 regs.
// Phase 1 mapping: L0=l4 L1=l0 L2=l1 L3=l2 L4=l3 L5=l5 L6=r0 L7=r1 L8=r2 L9=wh
// Phase 2 mapping: L0=wh L1=l1 L2=l3 L3=l0 L4=l4 L5=r0 L6=l5 L7=r1 L8=l2 L9=r2
// One LDS permute between them; swizzle slot = L ^ bit8(L).
// launch_bounds(256,2): VGPR cap 256 — r11's (256,4) cap of 128 made the
// allocator pick 64 VGPR and spill ~8MB scratch/dispatch (the regression).
__global__ __launch_bounds__(256, 2) void hqtcn_fused(
    const float* __restrict__ x,      // (16, 32, 128)
    const float* __restrict__ fc_w,   // (10, 256)
    const float* __restrict__ fc_b,   // (10,)
    const float* __restrict__ conv,   // (3, 10, 15)
    const float* __restrict__ pool,   // (3, 5, 3)
    float* __restrict__ out)          // (1936,)
{
    __shared__ float2 gmat[NGATES*16];     // 2944 B gate matrices
    __shared__ float2 pbuf[2][1024];       // 8 KB per-sample permute buffer
    __shared__ float  red[2][2];

    const int tid  = threadIdx.x;
    const int wid  = tid >> 6;
    const int lane = tid & 63;
    const int ws = wid >> 1;               // sample within block (0/1)
    const int wh = wid & 1;                // wave half within sample (0/1)
    const int s = blockIdx.x * 2 + ws;     // 968*2 = 1936 exact
    const int b = s / NWIN, w = s % NWIN;

    // ---- x loads (per wave; both halves load the same sample's features)
    float xv[4];
    #pragma unroll
    for (int j = 0; j < 4; ++j) {
        int f = lane + 64*j;
        xv[j] = x[b*4096 + (f >> 3)*128 + w + (f & 7)];
    }

    // ---- parallel gate build: thread (g, c) computes column c of gate g
    if (tid < 4*NGATES) {
        cpx Mc[4];
        build_gate_col(tid >> 2, tid & 3, conv, pool, Mc);
        #pragma unroll
        for (int r = 0; r < 4; ++r)
            gmat[(tid>>2)*16 + r*4 + (tid&3)] = make_float2(Mc[r].x, Mc[r].y);
    }

    // ---- angles (each wave computes all 10 for its sample)
    float cq[NQ], sq[NQ];
    #pragma unroll
    for (int e = 0; e < NQ; ++e) {
        float v = 0.f;
        #pragma unroll
        for (int j = 0; j < 4; ++j)
            v = fmaf(xv[j], fc_w[e*256 + lane + 64*j], v);
        #pragma unroll
        for (int off = 32; off >= 1; off >>= 1) v += __shfl_xor(v, off);
        float h = 0.5f * (v + fc_b[e]);
        __sincosf(h, &sq[e], &cq[e]);
    }
    __syncthreads();    // gmat ready

    // ---- init with g0..g4 absorbed: Wv[p] = G_p @ [cc',cs',sc',ss']
    v2f Wv[5][4];
    #pragma unroll
    for (int p = 0; p < 5; ++p) {
        float ca = cq[2*p], sa = sq[2*p], cb = cq[2*p+1], sb = sq[2*p+1];
        float u0 = ca*cb, u1 = ca*sb, u2 = sa*cb, u3_ = sa*sb;
        const float2* G = gmat + p*16;
        #pragma unroll
        for (int i = 0; i < 4; ++i) {
            float2 g0 = G[i*4+0], g1 = G[i*4+1], g2 = G[i*4+2], g3 = G[i*4+3];
            v2f acc = (v2f){g0.x*u0, g0.y*u0};
            acc = __builtin_elementwise_fma((v2f){u1,u1}, (v2f){g1.x,g1.y}, acc);
            acc = __builtin_elementwise_fma((v2f){u2,u2}, (v2f){g2.x,g2.y}, acc);
            acc = __builtin_elementwise_fma((v2f){u3_,u3_}, (v2f){g3.x,g3.y}, acc);
            Wv[p][i] = acc;
        }
    }
    // Phase-1 amp bits: k0=2*wh+r2, k1=2*r1+r0, k2=2*l5+l3, k3=2*l2+l1, k4=2*l0+l4
    const int l0 = lane&1, l1=(lane>>1)&1, l2=(lane>>2)&1,
              l3=(lane>>3)&1, l4=(lane>>4)&1, l5=(lane>>5)&1;
    v2f W2v = vsel(l5, vsel(l3, Wv[2][3], Wv[2][2]), vsel(l3, Wv[2][1], Wv[2][0]));
    v2f W3v = vsel(l2, vsel(l1, Wv[3][3], Wv[3][2]), vsel(l1, Wv[3][1], Wv[3][0]));
    v2f W4v = vsel(l0, vsel(l4, Wv[4][3], Wv[4][2]), vsel(l4, Wv[4][1], Wv[4][0]));
    v2f A  = cmulv(W2v, cmulv(W3v, W4v));
    v2f G0 = cmulv(A, vsel(wh, Wv[0][2], Wv[0][0]));   // r2 = 0
    v2f G1 = cmulv(A, vsel(wh, Wv[0][3], Wv[0][1]));   // r2 = 1
    v2f st[8];
    #pragma unroll
    for (int r = 0; r < 8; ++r) {
        v2f D = Wv[1][2*((r>>1)&1) + (r&1)];
        st[r] = cmulv((r >> 2) ? G1 : G0, D);
    }

    const float2* gm = gmat;

    // ---- Phase 1 (wave bit = logical 9; bits: 8=r2 7=r1 6=r0,
    //      5=l5(32) 4=l3(8) 3=l2(4) 2=l1(2) 1=l0(1) 0=l4(16))
    gateRR<2,1>(st, gm + 5*16);            // g5  {8,7}
    gateRL<0,32>(st, gm + 6*16, lane);     // g6  {6,5}
    gateLL<8,4>(st, gm + 7*16, lane);      // g7  {4,3}
    gateLL<2,1>(st, gm + 8*16, lane);      // g8  {2,1}
    crotRR<0,1>(st, gm + 10*16);           // g10 ctrl6->7
    crotLL<8,32>(st, gm + 11*16, lane);    // g11 ctrl4->5
    crotLL<2,4>(st, gm + 12*16, lane);     // g12 ctrl2->3
    crotLL<16,1>(st, gm + 13*16, lane);    // g13 ctrl0->1

    // ---- permute to phase-2 mapping (slot = L ^ bit8(L))
    {
        char* buf = (char*)&pbuf[ws][0];
        const int bw = l4 | (l0<<1) | (l1<<2) | (l2<<3) | (l3<<4) | (l5<<5) | (wh<<9);
        #pragma unroll
        for (int r = 0; r < 8; ++r) {
            int slot = (bw | ((r&1)<<6) | (((r>>1)&1)<<7) | (((r>>2)&1)<<8)) ^ ((r>>2)&1);
            *reinterpret_cast<v2f*>(buf + (slot<<3)) = st[r];
        }
        __syncthreads();
        const int br = (wh | (l1<<1) | (l3<<2) | (l0<<3) | (l4<<4) | (l5<<6) | (l2<<8)) ^ l2;
        #pragma unroll
        for (int r = 0; r < 8; ++r) {
            int slot = br | ((r&1)<<5) | (((r>>1)&1)<<7) | (((r>>2)&1)<<9);
            st[r] = *reinterpret_cast<const v2f*>(buf + (slot<<3));
        }
    }

    // ---- Phase 2 (wave bit = logical 0; bits: 9=r2 7=r1 5=r0,
    //      8=l2(4) 3=l0(1) 1=l1(2); idle: 2=l3 4=l4 6=l5)
    crotLR<4,2>(st, gm + 9*16, lane);      // g9  ctrl8(lane)->9(reg)
    gateRR<2,1>(st, gm + 14*16);           // g14 {9,7}
    gateRL<0,1>(st, gm + 15*16, lane);     // g15 {5,3}
    gateRR<1,0>(st, gm + 16*16);           // g16 {7,5}
    gateLL<1,2>(st, gm + 17*16, lane);     // g17 {3,1}
    crotRR<1,2>(st, gm + 18*16);           // g18 ctrl7->9
    crotLR<1,0>(st, gm + 19*16, lane);     // g19 ctrl3(lane)->5(reg)
    gateRR<2,0>(st, gm + 20*16);           // g20 {9,5}
    gateRL<0,2>(st, gm + 21*16, lane);     // g21 {5,1}
    crotRR<0,2>(st, gm + 22*16);           // g22 ctrl5->9

    // ---- <Z0>: logical bit 9 = reg bit 2
    float accp = 0.f, accm = 0.f;
    #pragma unroll
    for (int r = 0; r < 8; ++r) {
        v2f a = st[r];
        float p2 = fmaf(a.x, a.x, a.y*a.y);
        if (r & 4) accm += p2; else accp += p2;
    }
    float acc = accp - accm;
    #pragma unroll
    for (int off = 32; off >= 1; off >>= 1) acc += __shfl_xor(acc, off);
    if (lane == 0) red[ws][wh] = acc;
    __syncthreads();
    if (wh == 0 && lane == 0) out[s] = red[ws][0] + red[ws][1];
}

extern "C" void kernel_launch(void* const* d_in, const int* in_sizes, int n_in,
                              void* d_out, int out_size, void* d_ws, size_t ws_size,
                              hipStream_t stream) {
    const float* x     = (const float*)d_in[0];
    const float* fc_w  = (const float*)d_in[1];
    const float* fc_b  = (const float*)d_in[2];
    const float* convp = (const float*)d_in[3];
    const float* poolp = (const float*)d_in[4];
    float* out = (float*)d_out;

    hqtcn_fused<<<(16*NWIN)/2, 256, 0, stream>>>(x, fc_w, fc_b, convp, poolp, out);
}

// Round 13
// 24.653 us; speedup vs baseline: 1.4160x; 1.4160x over previous
//
#include <hip/hip_runtime.h>

#define NWIN 121
#define NQ 10
#define NGATES 23
#define WPB 4          // waves (samples) per block

typedef float v2f __attribute__((ext_vector_type(2)));

// type 0 = fused conv block (u3⊗u3 · XX·YY·ZZ · u3⊗u3), type 1 = CRot.
__device__ static const int dGT[NGATES] = {0,0,0,0,0,0,0,0,0, 1,1,1,1,1, 0,0,0,0, 1,1, 0,0, 1};
__device__ static const int dGL[NGATES] = {0,0,0,0,0,0,0,0,0, 0,0,0,0,0, 1,1,1,1, 1,1, 2,2, 2};
__device__ static const int dGP[NGATES] = {0,2,4,6,8,1,3,5,7, 0,1,2,3,4, 0,2,1,3, 0,1, 0,1, 0};

// ---- 4-phase register-resident schedule (g0..g4 absorbed into init) -------
// (schedule + swizzles verified bit-exact in rounds 6-10: absmax = 0)
__host__ __device__ constexpr int REGB[4][4] = {
    {5,6,7,8},{1,2,3,4},{0,1,3,5},{3,5,7,9}};
__host__ __device__ constexpr int LANEB[4][6] = {
    {0,1,2,3,4,9},{0,5,6,7,8,9},{2,4,6,7,8,9},{0,1,2,4,6,8}};

__host__ __device__ constexpr int hswz(int p, int L){
    return p==0 ? ((((L>>5)&1)<<1)|(((L>>6)&1)<<2)|(((L>>7)&1)<<3))
         : p==1 ? (((L>>4)&1) | ((((L>>5)&1)^((L>>6)&1))<<1) | (((L>>7)&1)<<2) | (((L>>8)&1)<<3))
         :        (((L>>4)&1) | (((L>>6)&1)<<1) | (((L>>8)&1)<<3));   // p=2
}
__host__ __device__ constexpr int offsL(int ph, int r){
    int o = 0;
    for (int k=0;k<4;++k) if ((r>>k)&1) o |= 1<<REGB[ph][k];
    return o;
}

struct cpx { float x, y; };
__device__ __forceinline__ cpx cmul(cpx a, cpx b){ return {a.x*b.x - a.y*b.y, a.x*b.y + a.y*b.x}; }
__device__ __forceinline__ cpx cadd(cpx a, cpx b){ return {a.x+b.x, a.y+b.y}; }
__device__ __forceinline__ cpx cscale(float s, cpx a){ return {s*a.x, s*a.y}; }
__device__ __forceinline__ cpx cexp_i(float t){ return {cosf(t), sinf(t)}; }
__device__ __forceinline__ cpx mulnegi(cpx z){ return {z.y, -z.x}; }   // -i*z
__device__ __forceinline__ cpx csel(int c, cpx a, cpx b){ return {c ? a.x : b.x, c ? a.y : b.y}; }

__device__ __forceinline__ void u3m(cpx A[2][2], float th, float ph, float de){
    float ct = cosf(0.5f*th), st = sinf(0.5f*th);
    cpx ed  = cexp_i(de);
    cpx ep  = cexp_i(ph);
    cpx epd = cexp_i(ph + de);
    A[0][0] = {ct, 0.f};
    A[0][1] = {-ed.x*st, -ed.y*st};
    A[1][0] = { ep.x*st,  ep.y*st};
    A[1][1] = { epd.x*ct, epd.y*ct};
}

// Build COLUMN c of fused gate g's 4x4 matrix. ALL array indices static
// (rule-#20 safe; runtime column choice via csel/cndmask — the r9 fix).
__device__ __forceinline__ void build_gate_col(int g, int c,
                                               const float* __restrict__ conv,
                                               const float* __restrict__ pool,
                                               cpx (&Mc)[4])
{
    int l = dGL[g], pi = dGP[g];
    if (dGT[g] == 0) {
        const float* W1 = conv + l*150 + pi*15;
        const float* W2 = conv + l*150 + (pi+1)*15;
        cpx A1[2][2], B1[2][2], A2[2][2], B2[2][2];
        u3m(A1, W1[0],  W1[1],  W1[2]);
        u3m(B1, W2[3],  W2[4],  W2[5]);
        u3m(A2, W1[9],  W1[10], W1[11]);
        u3m(B2, W2[12], W2[13], W2[14]);
        const int c1 = c >> 1, c2 = c & 1;
        cpx a1r0 = csel(c1, A1[0][1], A1[0][0]);
        cpx a1r1 = csel(c1, A1[1][1], A1[1][0]);
        cpx b1r0 = csel(c2, B1[0][1], B1[0][0]);
        cpx b1r1 = csel(c2, B1[1][1], B1[1][0]);
        cpx T[4];
        T[0] = cmul(a1r0, b1r0);
        T[1] = cmul(a1r0, b1r1);
        T[2] = cmul(a1r1, b1r0);
        T[3] = cmul(a1r1, b1r1);
        float tz = W1[6];
        cpx em = cexp_i(-0.5f*tz), ep = cexp_i(0.5f*tz);
        T[0] = cmul(em, T[0]); T[1] = cmul(ep, T[1]);
        T[2] = cmul(ep, T[2]); T[3] = cmul(em, T[3]);
        float ty = W1[7]; float cy = cosf(0.5f*ty), sy = sinf(0.5f*ty);
        cpx T2_[4];
        T2_[0] = cadd(cscale(cy,T[0]), mulnegi(cscale(-sy, T[3])));
        T2_[1] = cadd(cscale(cy,T[1]), mulnegi(cscale( sy, T[2])));
        T2_[2] = cadd(cscale(cy,T[2]), mulnegi(cscale( sy, T[1])));
        T2_[3] = cadd(cscale(cy,T[3]), mulnegi(cscale(-sy, T[0])));
        float tx = W1[8]; float cx = cosf(0.5f*tx), sx = sinf(0.5f*tx);
        cpx T3_[4];
        T3_[0] = cadd(cscale(cx,T2_[0]), mulnegi(cscale(sx, T2_[3])));
        T3_[1] = cadd(cscale(cx,T2_[1]), mulnegi(cscale(sx, T2_[2])));
        T3_[2] = cadd(cscale(cx,T2_[2]), mulnegi(cscale(sx, T2_[1])));
        T3_[3] = cadd(cscale(cx,T2_[3]), mulnegi(cscale(sx, T2_[0])));
        cpx K2[4][4];
        #pragma unroll
        for (int r1=0;r1<2;++r1)
        #pragma unroll
        for (int r2=0;r2<2;++r2)
        #pragma unroll
        for (int d1=0;d1<2;++d1)
        #pragma unroll
        for (int d2=0;d2<2;++d2)
            K2[2*r1+r2][2*d1+d2] = cmul(A2[r1][d1], B2[r2][d2]);
        #pragma unroll
        for (int r=0;r<4;++r) {
            cpx acc = {0.f, 0.f};
            #pragma unroll
            for (int m=0;m<4;++m) acc = cadd(acc, cmul(K2[r][m], T3_[m]));
            Mc[r] = acc;
        }
    } else {
        const float* Pp = pool + l*15 + pi*3;
        float phi = Pp[0], th = Pp[1], om = Pp[2];
        float ct = cosf(0.5f*th), st = sinf(0.5f*th);
        cpx z = {0.f, 0.f}, one = {1.f, 0.f};
        cpx m22 = cscale( ct, cexp_i(-0.5f*(phi+om)));
        cpx m32 = cscale( st, cexp_i(-0.5f*(phi-om)));
        cpx m23 = cscale(-st, cexp_i( 0.5f*(phi-om)));
        cpx m33 = cscale( ct, cexp_i( 0.5f*(phi+om)));
        Mc[0] = csel(c == 0, one, z);
        Mc[1] = csel(c == 1, one, z);
        Mc[2] = csel(c == 2, m22, csel(c == 3, m23, z));
        Mc[3] = csel(c == 2, m32, csel(c == 3, m33, z));
    }
}

// ---- sim helpers -----------------------------------------------------------

__device__ __forceinline__ v2f cfma(v2f m, v2f v, v2f acc) {
    v2f sw = {v.y, v.x};
    v2f my = {-m.y, m.y};
    v2f t = __builtin_elementwise_fma(my, sw, acc);
    v2f mx = {m.x, m.x};
    return __builtin_elementwise_fma(mx, v, t);
}
__device__ __forceinline__ v2f cmulv(v2f a, v2f b) { return cfma(a, b, (v2f){0.f,0.f}); }
__device__ __forceinline__ v2f vsel(int c, v2f a, v2f b) {
    return (v2f){ c ? a.x : b.x, c ? a.y : b.y };
}

// wave-local LDS fence: drain this wave's outstanding DS ops; no s_barrier.
__device__ __forceinline__ void wave_lds_fence() {
    asm volatile("s_waitcnt lgkmcnt(0)" ::: "memory");
}

// explicit matrix loads (issued early; consumed by *m gate forms below) ------
__device__ __forceinline__ void load16(const float2* __restrict__ g, v2f (&m)[16]) {
    const float4* g4 = reinterpret_cast<const float4*>(g);
    #pragma unroll
    for (int k = 0; k < 8; ++k) {
        float4 t = g4[k];
        m[2*k]   = (v2f){t.x, t.y};
        m[2*k+1] = (v2f){t.z, t.w};
    }
}
__device__ __forceinline__ void load4(const float2* __restrict__ g, v2f (&c4)[4]) {
    const float4* g4 = reinterpret_cast<const float4*>(g);
    float4 a = g4[5], b = g4[7];
    c4[0] = (v2f){a.x,a.y}; c4[1] = (v2f){a.z,a.w};   // m22 m23
    c4[2] = (v2f){b.x,b.y}; c4[3] = (v2f){b.z,b.w};   // m32 m33
}

// dense 4x4 gate on register bits P1,P2 (matrix preloaded).
template<int P1, int P2>
__device__ __forceinline__ void gate4m(v2f (&st)[16], const v2f (&m)[16]) {
    constexpr int M1 = 1 << P1, M2 = 1 << P2;
    #pragma unroll
    for (int b = 0; b < 16; ++b) {
        if (b & (M1 | M2)) continue;
        v2f v0 = st[b], v1 = st[b|M2], v2 = st[b|M1], v3 = st[b|M1|M2];
        #pragma unroll
        for (int row = 0; row < 4; ++row) {
            v2f acc = cfma(m[row*4+0], v0, (v2f){0.f, 0.f});
            acc = cfma(m[row*4+1], v1, acc);
            acc = cfma(m[row*4+2], v2, acc);
            acc = cfma(m[row*4+3], v3, acc);
            st[b | ((row>>1) ? M1 : 0) | ((row&1) ? M2 : 0)] = acc;
        }
    }
}

// CRot on register bits: P1 = ctrl, P2 = tgt (2x2 block preloaded).
template<int P1, int P2>
__device__ __forceinline__ void crot4m(v2f (&st)[16], const v2f (&c4)[4]) {
    constexpr int M1 = 1 << P1, M2 = 1 << P2;
    #pragma unroll
    for (int b = 0; b < 16; ++b) {
        if (!(b & M1) || (b & M2)) continue;
        v2f v2_ = st[b], v3_ = st[b|M2];
        st[b]    = cfma(c4[1], v3_, cmulv(c4[0], v2_));
        st[b|M2] = cfma(c4[3], v3_, cmulv(c4[2], v2_));
    }
}

// Mixed CRot: ctrl bit at reg pos PCTRL, tgt bit at LANE bit LBIT.
template<int PCTRL, int LBIT>
__device__ __forceinline__ void crotxm(v2f (&st)[16], const v2f (&c4)[4], int lane) {
    const int beta = (lane >> LBIT) & 1;
    v2f S0 = vsel(beta, c4[3], c4[0]);
    v2f S1 = vsel(beta, c4[2], c4[1]);
    constexpr int M1 = 1 << PCTRL;
    #pragma unroll
    for (int b = 0; b < 16; ++b) {
        if (!(b & M1)) continue;         // ctrl = 1 amps
        v2f u = st[b], p;
        p.x = __shfl_xor(u.x, 1 << LBIT);
        p.y = __shfl_xor(u.y, 1 << LBIT);
        st[b] = cfma(S1, p, cmulv(S0, u));
    }
}

// Mixed dense gate: one bit at reg pos PREG, other at LANE bit LBIT.
template<int PREG, int LBIT>
__device__ __forceinline__ void gate4xm(v2f (&st)[16], const v2f (&m)[16], int lane) {
    const int beta = (lane >> LBIT) & 1;
    v2f A00 = vsel(beta, m[5],  m[0]);
    v2f A01 = vsel(beta, m[4],  m[1]);
    v2f A02 = vsel(beta, m[7],  m[2]);
    v2f A03 = vsel(beta, m[6],  m[3]);
    v2f A10 = vsel(beta, m[13], m[8]);
    v2f A11 = vsel(beta, m[12], m[9]);
    v2f A12 = vsel(beta, m[15], m[10]);
    v2f A13 = vsel(beta, m[14], m[11]);
    constexpr int M1 = 1 << PREG;
    #pragma unroll
    for (int b = 0; b < 16; ++b) {
        if (b & M1) continue;
        v2f u0 = st[b], u1 = st[b|M1], p0, p1;
        p0.x = __shfl_xor(u0.x, 1 << LBIT); p0.y = __shfl_xor(u0.y, 1 << LBIT);
        p1.x = __shfl_xor(u1.x, 1 << LBIT); p1.y = __shfl_xor(u1.y, 1 << LBIT);
        v2f r0 = cfma(A03, p1, cfma(A02, u1, cfma(A01, p0, cmulv(A00, u0))));
        v2f r1 = cfma(A13, p1, cfma(A12, u1, cfma(A11, p0, cmulv(A10, u0))));
        st[b] = r0; st[b|M1] = r1;
    }
}

template<int PH>
__device__ __forceinline__ int base_of(int lane) {
    int b = 0;
    #pragma unroll
    for (int j = 0; j < 6; ++j) b |= ((lane >> j) & 1) << LANEB[PH][j];
    return b;
}

// LDS re-permute (double-buffered, wave-local) from phase P to phase P+1.
template<int P>
__device__ __forceinline__ void permute(v2f (&st)[16], char* buf, int lane) {
    int bw0 = base_of<P>(lane);
    int bw = (bw0 ^ hswz(P, bw0)) << 3;
    #pragma unroll
    for (int r = 0; r < 16; ++r) {
        const int o = offsL(P, r);
        const int C = (o ^ hswz(P, o)) << 3;
        *reinterpret_cast<v2f*>(buf + (bw ^ C)) = st[r];
    }
    wave_lds_fence();
    int br0 = base_of<P+1>(lane);
    int br = (br0 ^ hswz(P, br0)) << 3;
    #pragma unroll
    for (int r = 0; r < 16; ++r) {
        const int o = offsL(P+1, r);
        const int C = (o ^ hswz(P, o)) << 3;
        st[r] = *reinterpret_cast<const v2f*>(buf + (br ^ C));
    }
}

// Single fused kernel. Block = 256 threads = 4 waves = 4 samples.
// r13: explicit software-pipelined gate-matrix double-buffer (mA/mB/cA/cB):
// every ds_read batch issues >=1 full gate (~256 FMA-cycles) before its use;
// next-phase prefetches ride across each permute's lgkmcnt(0) drain.
__global__ __launch_bounds__(256, 2) void hqtcn_fused(
    const float* __restrict__ x,      // (16, 32, 128)
    const float* __restrict__ fc_w,   // (10, 256)
    const float* __restrict__ fc_b,   // (10,)
    const float* __restrict__ conv,   // (3, 10, 15)
    const float* __restrict__ pool,   // (3, 5, 3)
    float* __restrict__ out)          // (1936,)
{
    __shared__ float2 gmat[NGATES*16];        // 2944 B gate matrices
    __shared__ float2 pbuf[WPB][2][1024];     // 2 x 8 KB per-wave permute bufs

    const int tid  = threadIdx.x;
    const int wid  = tid >> 6;
    const int lane = tid & 63;
    const int s = blockIdx.x * WPB + wid;     // 484*4 = 1936 exact
    const int b = s / NWIN, w = s % NWIN;

    // ---- issue x loads early (lane handles features f = 4*lane + j)
    float xv[4];
    #pragma unroll
    for (int j = 0; j < 4; ++j) {
        int f = 4*lane + j;
        xv[j] = x[b*4096 + (f >> 3)*128 + w + (f & 7)];
    }

    // ---- parallel gate build: thread (g, c) computes column c of gate g
    if (tid < 4*NGATES) {
        cpx Mc[4];
        build_gate_col(tid >> 2, tid & 3, conv, pool, Mc);
        #pragma unroll
        for (int r = 0; r < 4; ++r)
            gmat[(tid>>2)*16 + r*4 + (tid&3)] = make_float2(Mc[r].x, Mc[r].y);
    }

    // ---- angles (per wave); fc_w row slice is one aligned float4 per e
    float cq[NQ], sq[NQ];
    #pragma unroll
    for (int e = 0; e < NQ; ++e) {
        float4 wv = *reinterpret_cast<const float4*>(fc_w + e*256 + 4*lane);
        float v = fmaf(xv[0], wv.x, fmaf(xv[1], wv.y, fmaf(xv[2], wv.z, xv[3]*wv.w)));
        #pragma unroll
        for (int off = 32; off >= 1; off >>= 1) v += __shfl_xor(v, off);
        float h = 0.5f * (v + fc_b[e]);
        __sincosf(h, &sq[e], &cq[e]);
    }
    __syncthreads();    // the only block-wide barrier (gmat ready)

    // ---- init: apply g0..g4 analytically. W[p] = G_p @ [cc',cs',sc',ss']
    v2f W[5][4];
    #pragma unroll
    for (int p = 0; p < 5; ++p) {
        float ca = cq[2*p], sa = sq[2*p], cb = cq[2*p+1], sb = sq[2*p+1];
        float u0 = ca*cb, u1 = ca*sb, u2 = sa*cb, u3_ = sa*sb;
        const float2* G = gmat + p*16;
        #pragma unroll
        for (int i = 0; i < 4; ++i) {
            float2 g0 = G[i*4+0], g1 = G[i*4+1], g2 = G[i*4+2], g3 = G[i*4+3];
            v2f acc = (v2f){g0.x*u0, g0.y*u0};
            acc = __builtin_elementwise_fma((v2f){u1,u1}, (v2f){g1.x,g1.y}, acc);
            acc = __builtin_elementwise_fma((v2f){u2,u2}, (v2f){g2.x,g2.y}, acc);
            acc = __builtin_elementwise_fma((v2f){u3_,u3_}, (v2f){g3.x,g3.y}, acc);
            W[p][i] = acc;
        }
    }
    // Phase-A mapping: reg bits = logical {5,6,7,8}; lane bits = {0,1,2,3,4,9}
    const int l0 = lane&1, l1=(lane>>1)&1, l2=(lane>>2)&1,
              l3=(lane>>3)&1, l4=(lane>>4)&1, l5=(lane>>5)&1;
    v2f W3k = vsel(l3, vsel(l2, W[3][3], W[3][2]), vsel(l2, W[3][1], W[3][0]));
    v2f W4k = vsel(l1, vsel(l0, W[4][3], W[4][2]), vsel(l0, W[4][1], W[4][0]));
    v2f UL  = cmulv(W3k, W4k);
    v2f W2lo = vsel(l4, W[2][1], W[2][0]);
    v2f W2hi = vsel(l4, W[2][3], W[2][2]);
    v2f P0v = cmulv(UL, vsel(l5, W[0][2], W[0][0]));
    v2f P1v = cmulv(UL, vsel(l5, W[0][3], W[0][1]));
    v2f PW[2][4];
    #pragma unroll
    for (int j = 0; j < 4; ++j) {
        PW[0][j] = cmulv(P0v, W[1][j]);
        PW[1][j] = cmulv(P1v, W[1][j]);
    }
    v2f st[16];
    #pragma unroll
    for (int r = 0; r < 16; ++r)
        st[r] = cmulv(PW[(r>>3)&1][(r>>1)&3], (r&1) ? W2hi : W2lo);

    const float2* gm = gmat;
    v2f mA[16], mB[16], cA[4], cB[4];

    // ---- Phase A: reg {5,6,7,8}, lane {0,1,2,3,4,9}
    load16(gm + 5*16, mA); load16(gm + 6*16, mB);
    load4 (gm + 10*16, cA); load4(gm + 9*16, cB);
    gate4m<3,2>(st, mA);                 // g5  {8,7}
    load16(gm + 7*16, mA);               // prefetch g7 (phase B)
    gate4m<1,0>(st, mB);                 // g6  {6,5}
    load16(gm + 8*16, mB);               // prefetch g8 (phase B)
    crot4m<1,2>(st, cA);                 // g10 ctrl6->7
    load4(gm + 12*16, cA);               // prefetch g12 (phase B)
    crotxm<3,5>(st, cB, lane);           // g9  ctrl8(reg3)->9(lane5)
    load4(gm + 11*16, cB);               // prefetch g11 (phase B)
    permute<0>(st, (char*)&pbuf[wid][0][0], lane);
    // ---- Phase B: reg {1,2,3,4}, lane {0,5,6,7,8,9}
    gate4m<3,2>(st, mA);                 // g7  {4,3}
    load16(gm + 15*16, mA);              // prefetch g15 (phase D)
    gate4m<1,0>(st, mB);                 // g8  {2,1}
    load16(gm + 17*16, mB);              // prefetch g17 (phase D)
    crot4m<1,2>(st, cA);                 // g12 ctrl2->3
    load4(gm + 13*16, cA);               // prefetch g13 (phase D)
    crotxm<3,1>(st, cB, lane);           // g11 ctrl4(reg3)->5(lane1)
    permute<1>(st, (char*)&pbuf[wid][1][0], lane);
    // ---- Phase D: reg {0,1,3,5}, lane {2,4,6,7,8,9}
    crot4m<0,1>(st, cA);                 // g13 ctrl0->1
    load4(gm + 18*16, cA);               // prefetch g18 (phase E)
    gate4m<3,2>(st, mA);                 // g15 {5,3}
    load16(gm + 14*16, mA);              // prefetch g14 (phase E)
    gate4m<2,1>(st, mB);                 // g17 {3,1}
    load16(gm + 16*16, mB);              // prefetch g16 (phase E)
    load4(gm + 19*16, cB);               // prefetch g19 (phase E)
    permute<2>(st, (char*)&pbuf[wid][0][0], lane);
    // ---- Phase E: reg {3,5,7,9}, lane {0,1,2,4,6,8}
    gate4m<3,2>(st, mA);                 // g14 {9,7}
    load16(gm + 20*16, mA);              // prefetch g20
    gate4m<2,1>(st, mB);                 // g16 {7,5}
    load16(gm + 21*16, mB);              // prefetch g21
    crot4m<2,3>(st, cA);                 // g18 ctrl7->9
    load4(gm + 22*16, cA);               // prefetch g22
    crot4m<0,1>(st, cB);                 // g19 ctrl3->5
    gate4m<3,1>(st, mA);                 // g20 {9,5}
    gate4xm<1,1>(st, mB, lane);          // g21 {5(reg1), 1(lane1)}
    crot4m<1,3>(st, cA);                 // g22 ctrl5->9

    // ---- <Z0>: logical bit 9 at reg pos 3 in phase E.
    float accp = 0.f, accm = 0.f;
    #pragma unroll
    for (int r = 0; r < 16; ++r) {
        v2f a = st[r];
        float p2 = fmaf(a.x, a.x, a.y*a.y);
        if ((r >> 3) & 1) accm += p2; else accp += p2;
    }
    float acc = accp - accm;
    #pragma unroll
    for (int off = 32; off >= 1; off >>= 1) acc += __shfl_xor(acc, off);
    if (lane == 0) out[s] = acc;
}

extern "C" void kernel_launch(void* const* d_in, const int* in_sizes, int n_in,
                              void* d_out, int out_size, void* d_ws, size_t ws_size,
                              hipStream_t stream) {
    const float* x     = (const float*)d_in[0];
    const float* fc_w  = (const float*)d_in[1];
    const float* fc_b  = (const float*)d_in[2];
    const float* convp = (const float*)d_in[3];
    const float* poolp = (const float*)d_in[4];
    float* out = (float*)d_out;

    hqtcn_fused<<<(16*NWIN)/WPB, 64*WPB, 0, stream>>>(x, fc_w, fc_b, convp, poolp, out);
}